// Round 5
// baseline (166.909 us; speedup 1.0000x reference)
//
#include <hip/hip_runtime.h>
#include <hip/hip_bf16.h>

namespace {

constexpr int MM = 64;
constexpr int KK = 4096;
constexpr int NN = 11008;
constexpr int NZROW = NN / 8;        // 1376
constexpr int WCOL = 16;             // cols per wave = one MFMA col-tile
constexpr int BCOL = 64;             // cols per block (4 independent waves)
constexpr int KSPLIT = 8;
constexpr int KSEG = KK / KSPLIT;    // 512
constexpr int BK = 32;               // k per chunk (one MFMA K)
constexpr int NCH = KSEG / BK;       // 16 chunks
constexpr int NG = KSEG / 128;       // 4 scale-groups per kseg
constexpr int NT = NN / BCOL;        // 172 col-tiles -> grid 1376
constexpr size_t WS_NEED = (size_t)KSPLIT * MM * NN * 4;  // 22.5 MB partials

typedef float f32x4 __attribute__((ext_vector_type(4)));
typedef short s16x8 __attribute__((ext_vector_type(8)));
typedef int   i32x4 __attribute__((ext_vector_type(4)));

__device__ __forceinline__ int pack_bf16(float a, float b) {
  union { __hip_bfloat162 h; int i; } u;
  u.h.x = __float2bfloat16(a);
  u.h.y = __float2bfloat16(b);
  return u.i;
}

// fallback path only: out[m][n] = bias[n], atomics on top
__global__ __launch_bounds__(256) void prep_kernel(
    const float* __restrict__ bias, float* __restrict__ out)
{
  const int i = blockIdx.x * 256 + threadIdx.x;
  out[i] = bias[i % NN];
}

// ws path: out = bias + sum of KSPLIT partials
__global__ __launch_bounds__(256) void reduce_kernel(
    const float* __restrict__ ws, const float* __restrict__ bias,
    float* __restrict__ out)
{
  const int i4 = (blockIdx.x * 256 + threadIdx.x) * 4;
  f32x4 acc = *(const f32x4*)(bias + (i4 % NN));
  #pragma unroll
  for (int s = 0; s < KSPLIT; ++s)
    acc += *(const f32x4*)(ws + (size_t)s * (MM * NN) + i4);
  *(f32x4*)(out + i4) = acc;
}

// R10: occupancy fix. R9's profile showed the truth: 65 us at 300 GB/s,
// occupancy 12%, VALUBusy 16% -> latency-bound with ~1 wave/SIMD exposed
// to every miss. This version keeps the zero-LDS zero-barrier inner loop
// (proven numerics, absmax 0.125) but splits work 4x finer: 16 cols per
// wave, KSPLIT=8 across blocks -> 1376 blocks x 4 independent waves =
// 21.5 waves/CU, so TLP hides L2/HBM latency instead of prefetch depth.
// Per-chunk issue order: raw A fp32 loads, then qw prefetch, then packs
// (the A-wait therefore leaves the newer qw prefetch outstanding).
// Registers ~85 (acc 16 + A raw 32 + rings/addr), bounds (256,5) cap 102.
template<bool ATOMIC>
__global__ __launch_bounds__(256, 5) void gptq_gemm_kernel(
    const float* __restrict__ x, const int* __restrict__ qw,
    const int* __restrict__ qz, const float* __restrict__ scales,
    float* __restrict__ out)
{
  const int tid  = threadIdx.x;
  const int wave = tid >> 6;
  const int lane = tid & 63;
  const int c    = lane & 15;
  const int quad = lane >> 4;

  const int ks     = blockIdx.x & 7;
  const int nt     = blockIdx.x >> 3;
  const int n0     = nt * BCOL;
  const int kbase0 = ks * KSEG;
  const int grp0   = kbase0 >> 7;          // scale-group base = ks*4

  const int ncol = n0 + wave * WCOL + c;   // this wave's single col-tile

  // B: qw row (kbase0/8 + quad), col ncol; chunk i advances 4 qw-rows.
  // 16 lanes x 4B = 64B contiguous per quad-row, fully used.
  const int* qwb = qw + ((size_t)(kbase0 >> 3) + quad) * NN + ncol;
  // A: row (r*16+c), k = kbase0 + i*32 + quad*8 (fp32, L2-resident 1 MB)
  const float* xab = x + (size_t)c * KK + kbase0 + quad * 8;

  f32x4 acc[4];
  #pragma unroll
  for (int r = 0; r < 4; ++r) acc[r] = {0.f, 0.f, 0.f, 0.f};

  int   pB[4];           // qweight ring, depth-3
  float pS[2];           // scale prefetch
  int   pZ[2];           // qzero prefetch
  float s0, C0;          // current-group dequant constants

  auto pfB = [&](int i) { pB[i & 3] = qwb[(size_t)i * 4 * NN]; };
  auto pfS = [&](int g) {
    const int sl = g & 1;
    pS[sl] = scales[(size_t)(grp0 + g) * NN + ncol];
    pZ[sl] = qz[(size_t)(grp0 + g) * NZROW + (ncol >> 3)];
  };
  auto setSC = [&](int g) {
    const int sl = g & 1;
    const int sh = (ncol & 7) * 4;
    s0 = pS[sl];
    C0 = __int_as_float(0x4B000000 + ((pZ[sl] >> sh) & 15) + 1);
  };
  auto dq8 = [&](int v) -> i32x4 {
    i32x4 p;
    p.x = pack_bf16(s0 * (__int_as_float(((v      ) & 15) | 0x4B000000) - C0),
                    s0 * (__int_as_float(((v >>  4) & 15) | 0x4B000000) - C0));
    p.y = pack_bf16(s0 * (__int_as_float(((v >>  8) & 15) | 0x4B000000) - C0),
                    s0 * (__int_as_float(((v >> 12) & 15) | 0x4B000000) - C0));
    p.z = pack_bf16(s0 * (__int_as_float(((v >> 16) & 15) | 0x4B000000) - C0),
                    s0 * (__int_as_float(((v >> 20) & 15) | 0x4B000000) - C0));
    p.w = pack_bf16(s0 * (__int_as_float(((v >> 24) & 15) | 0x4B000000) - C0),
                    s0 * (__int_as_float(((v >> 28) & 15) | 0x4B000000) - C0));
    return p;
  };

  // ---- prologue ----
  pfS(0);
  pfB(0); pfB(1); pfB(2);
  setSC(0);
  pfS(1);

  // fully unrolled: ring indices compile-time, no scratch
  #pragma unroll
  for (int i = 0; i < NCH; ++i) {
    // 1) issue raw A loads (oldest in this iteration)
    f32x4 a0[4], a1[4];
    #pragma unroll
    for (int r = 0; r < 4; ++r) {
      const float* xa = xab + (size_t)r * 16 * KK + i * BK;
      a0[r] = *(const f32x4*)xa;
      a1[r] = *(const f32x4*)(xa + 4);
    }
    // 2) issue qw prefetch AFTER A loads: the pack's A-wait below leaves it in flight
    if (i + 3 < NCH) pfB(i + 3);

    // 3) dequant B fragment (pB[i&3] loaded 3 chunks ago)
    union { i32x4 i4; s16x8 s8; } ub;
    ub.i4 = dq8(pB[i & 3]);

    // 4) pack A + MFMA
    #pragma unroll
    for (int r = 0; r < 4; ++r) {
      union { i32x4 i4; s16x8 s8; } ua;
      ua.i4.x = pack_bf16(a0[r].x, a0[r].y);
      ua.i4.y = pack_bf16(a0[r].z, a0[r].w);
      ua.i4.z = pack_bf16(a1[r].x, a1[r].y);
      ua.i4.w = pack_bf16(a1[r].z, a1[r].w);
      acc[r] = __builtin_amdgcn_mfma_f32_16x16x32_bf16(ua.s8, ub.s8, acc[r], 0, 0, 0);
    }

    if ((i & 3) == 3) {
      const int g = i >> 2;
      if (g + 1 < NG) { setSC(g + 1); if (g + 2 < NG) pfS(g + 2); }
    }
  }

  // ---- epilogue: rows r*16 + quad*4 + j, col ncol ----
  if (ATOMIC) {
    #pragma unroll
    for (int r = 0; r < 4; ++r) {
      const f32x4 a = acc[r];
      float* op = out + (size_t)(r * 16 + quad * 4) * NN + ncol;
      atomicAdd(&op[0],      a.x);
      atomicAdd(&op[NN],     a.y);
      atomicAdd(&op[2 * NN], a.z);
      atomicAdd(&op[3 * NN], a.w);
    }
  } else {
    float* wsp = out + (size_t)ks * (MM * NN);
    #pragma unroll
    for (int r = 0; r < 4; ++r) {
      const f32x4 a = acc[r];
      float* op = wsp + (size_t)(r * 16 + quad * 4) * NN + ncol;
      op[0]      = a.x;
      op[NN]     = a.y;
      op[2 * NN] = a.z;
      op[3 * NN] = a.w;
    }
  }
}

} // namespace

extern "C" void kernel_launch(void* const* d_in, const int* in_sizes, int n_in,
                              void* d_out, int out_size, void* d_ws, size_t ws_size,
                              hipStream_t stream) {
  const float* x      = (const float*)d_in[0];
  const int*   qw     = (const int*)d_in[1];
  const int*   qz     = (const int*)d_in[2];
  const float* scales = (const float*)d_in[3];
  const float* bias   = (const float*)d_in[4];
  float* out = (float*)d_out;

  if (ws_size >= WS_NEED) {
    float* ws = (float*)d_ws;
    gptq_gemm_kernel<false><<<NT * KSPLIT, 256, 0, stream>>>(x, qw, qz, scales, ws);
    reduce_kernel<<<(MM * NN) / 1024, 256, 0, stream>>>(ws, bias, out);
  } else {
    prep_kernel<<<(MM * NN) / 256, 256, 0, stream>>>(bias, out);
    gptq_gemm_kernel<true><<<NT * KSPLIT, 256, 0, stream>>>(x, qw, qz, scales, out);
  }
}

// Round 6
// 102.493 us; speedup vs baseline: 1.6285x; 1.6285x over previous
//
#include <hip/hip_runtime.h>
#include <hip/hip_bf16.h>

namespace {

constexpr int MM = 64;
constexpr int KK = 4096;
constexpr int NN = 11008;
constexpr int NZROW = NN / 8;        // 1376
constexpr int BCOL = 128;            // cols per block = 4 waves x 32
constexpr int KSPLIT = 8;
constexpr int KSEG = KK / KSPLIT;    // 512
constexpr int BK = 32;               // k per chunk (one MFMA K)
constexpr int NCH = KSEG / BK;       // 16 chunks per kseg
constexpr int NG = KSEG / 128;       // 4 scale-groups per kseg
constexpr int NT = NN / BCOL;        // 86 col-tiles -> grid 688
constexpr int NCHT = KK / BK;        // 128 chunks total (xbt blocks)
// ws layout: [0, 22.5MB) fp32 partials; [22.5MB, +512KB) bf16 xbt
constexpr size_t XBT_OFF = (size_t)KSPLIT * MM * NN * 4;     // 22,544,384 (16B aligned)
constexpr size_t WS_NEED = XBT_OFF + (size_t)MM * KK * 2;    // +512 KB

typedef float f32x4 __attribute__((ext_vector_type(4)));
typedef short s16x8 __attribute__((ext_vector_type(8)));
typedef int   i32x4 __attribute__((ext_vector_type(4)));

__device__ __forceinline__ int pack_bf16(float a, float b) {
  union { __hip_bfloat162 h; int i; } u;
  u.h.x = __float2bfloat16(a);
  u.h.y = __float2bfloat16(b);
  return u.i;
}

// One-time x shuffle: fp32 [64][4096] -> bf16 fragment-block layout.
// Block ci (k-chunk), row-tile r: 64 lanes' 16-B A-fragments contiguous:
//   xbt[((ci*4 + r)*64 + lane)*8 + j] = bf16(x[r*16 + (lane&15)][ci*32 + (lane>>4)*8 + j])
// Hot-loop A load then = 64 lanes x consecutive 16 B = 1 KB contiguous.
// Read side: each thread reads 32 contiguous bytes (fine); write side
// perfectly coalesced. 32K threads total, ~2 us.
__global__ __launch_bounds__(256) void xcvt_kernel(
    const float* __restrict__ x, unsigned short* __restrict__ xbt)
{
  const int tg = blockIdx.x * 256 + threadIdx.x;   // 0 .. 32767
  const int l  = tg & 63;
  const int r  = (tg >> 6) & 3;
  const int ci = tg >> 8;
  const int m  = r * 16 + (l & 15);
  const int k  = ci * BK + (l >> 4) * 8;
  const float* xp = x + (size_t)m * KK + k;
  const f32x4 a0 = *(const f32x4*)xp;
  const f32x4 a1 = *(const f32x4*)(xp + 4);
  i32x4 p;
  p.x = pack_bf16(a0.x, a0.y);
  p.y = pack_bf16(a0.z, a0.w);
  p.z = pack_bf16(a1.x, a1.y);
  p.w = pack_bf16(a1.z, a1.w);
  *(i32x4*)(xbt + (size_t)tg * 8) = p;
}

// fallback path only: out[m][n] = bias[n], atomics on top
__global__ __launch_bounds__(256) void prep_kernel(
    const float* __restrict__ bias, float* __restrict__ out)
{
  const int i = blockIdx.x * 256 + threadIdx.x;
  out[i] = bias[i % NN];
}

// ws path: out = bias + sum of KSPLIT partials
__global__ __launch_bounds__(256) void reduce_kernel(
    const float* __restrict__ ws, const float* __restrict__ bias,
    float* __restrict__ out)
{
  const int i4 = (blockIdx.x * 256 + threadIdx.x) * 4;
  f32x4 acc = *(const f32x4*)(bias + (i4 % NN));
  #pragma unroll
  for (int s = 0; s < KSPLIT; ++s)
    acc += *(const f32x4*)(ws + (size_t)s * (MM * NN) + i4);
  *(f32x4*)(out + i4) = acc;
}

// R11: coalescing fix. R10's post-mortem: occupancy 12->51% made the gemm
// SLOWER (65->94 us) with VALUBusy pinned at 17% and HBM at 5% -> the
// bottleneck is the per-CU vector-memory request pipe, saturated by
// uncoalesced A-fragment loads (consecutive lanes 16 KB apart = 64 cache
// lines per instruction). Here A comes from the pre-shuffled xbt, so each
// A-fragment load is 1 KB fully contiguous (~4-8 lines). B stays
// register-direct (one qweight dword = one MFMA B-fragment; exact 2^23
// dequant, single rounding -> absmax unchanged). Zero LDS, zero barriers.
// Wave owns 32 cols: 8 MFMAs per 4 A-loads + 2 qw dwords per chunk.
// Grid 688 x 4 waves ~= 10.7 waves/CU.
template<bool WSP>
__global__ __launch_bounds__(256, 4) void gptq_gemm_kernel(
    const float* __restrict__ x, const int* __restrict__ qw,
    const int* __restrict__ qz, const float* __restrict__ scales,
    const unsigned short* __restrict__ xbt, float* __restrict__ out)
{
  const int tid  = threadIdx.x;
  const int wave = tid >> 6;
  const int lane = tid & 63;
  const int c    = lane & 15;
  const int quad = lane >> 4;

  const int ks     = blockIdx.x & 7;
  const int nt     = blockIdx.x >> 3;
  const int n0     = nt * BCOL;
  const int kbase0 = ks * KSEG;
  const int grp0   = kbase0 >> 7;          // scale-group base = ks*4

  const int ncol = n0 + wave * 32 + c;     // t=0 col; t=1 is ncol+16

  // B: qw row (kbase0/8 + quad), col ncol; chunk i advances 4 qw-rows
  const int* qwb = qw + ((size_t)(kbase0 >> 3) + quad) * NN + ncol;
  // A (WSP): fragment block base; chunk i at +i*2048, row-tile r at +r*512
  const unsigned short* xbb = xbt + (size_t)(ks * NCH) * 2048 + lane * 8;
  // A (fallback): raw fp32
  const float* xab = x + (size_t)c * KK + kbase0 + quad * 8;

  f32x4 acc[8];   // acc[r*2+t]
  #pragma unroll
  for (int t = 0; t < 8; ++t) acc[t] = {0.f, 0.f, 0.f, 0.f};

  s16x8 pA[2][4];        // A fragments, depth-1 ring (L2-hit latency)
  int   pB0[4], pB1[4];  // qweight ring, depth-3 (cold HBM stream)
  float pS0[2], pS1[2];  // scales
  int   pZ0[2], pZ1[2];  // qzeros
  float s0, s1, C0, C1;  // current-group dequant constants

  auto ldA = [&](int i) {
    const unsigned short* xp = xbb + (size_t)i * 2048;
    #pragma unroll
    for (int r = 0; r < 4; ++r)
      pA[i & 1][r] = *(const s16x8*)(xp + r * 512);
  };
  auto pfB = [&](int i) {
    const int* qp = qwb + (size_t)i * 4 * NN;
    pB0[i & 3] = qp[0];
    pB1[i & 3] = qp[16];
  };
  auto pfS = [&](int g) {
    const int sl = g & 1;
    const float* sp = scales + (size_t)(grp0 + g) * NN + ncol;
    pS0[sl] = sp[0];
    pS1[sl] = sp[16];
    const int* zp = qz + (size_t)(grp0 + g) * NZROW + (ncol >> 3);
    pZ0[sl] = zp[0];
    pZ1[sl] = zp[2];   // (ncol+16)>>3 == (ncol>>3)+2
  };
  auto setSC = [&](int g) {
    const int sl = g & 1;
    const int sh = (ncol & 7) * 4;       // same nibble for ncol and ncol+16
    s0 = pS0[sl];
    s1 = pS1[sl];
    C0 = __int_as_float(0x4B000000 + ((pZ0[sl] >> sh) & 15) + 1);
    C1 = __int_as_float(0x4B000000 + ((pZ1[sl] >> sh) & 15) + 1);
  };
  auto dq8 = [&](int v, float s, float C) -> i32x4 {
    i32x4 p;
    p.x = pack_bf16(s * (__int_as_float(((v      ) & 15) | 0x4B000000) - C),
                    s * (__int_as_float(((v >>  4) & 15) | 0x4B000000) - C));
    p.y = pack_bf16(s * (__int_as_float(((v >>  8) & 15) | 0x4B000000) - C),
                    s * (__int_as_float(((v >> 12) & 15) | 0x4B000000) - C));
    p.z = pack_bf16(s * (__int_as_float(((v >> 16) & 15) | 0x4B000000) - C),
                    s * (__int_as_float(((v >> 20) & 15) | 0x4B000000) - C));
    p.w = pack_bf16(s * (__int_as_float(((v >> 24) & 15) | 0x4B000000) - C),
                    s * (__int_as_float(((v >> 28) & 15) | 0x4B000000) - C));
    return p;
  };
  auto ldA_f32 = [&](int i, int r) -> s16x8 {   // fallback only
    const float* xa = xab + (size_t)r * 16 * KK + i * BK;
    const f32x4 a0 = *(const f32x4*)xa;
    const f32x4 a1 = *(const f32x4*)(xa + 4);
    union { i32x4 i4; s16x8 s8; } ua;
    ua.i4.x = pack_bf16(a0.x, a0.y);
    ua.i4.y = pack_bf16(a0.z, a0.w);
    ua.i4.z = pack_bf16(a1.x, a1.y);
    ua.i4.w = pack_bf16(a1.z, a1.w);
    return ua.s8;
  };

  // ---- prologue ----
  pfS(0);
  pfB(0); pfB(1); pfB(2);
  if (WSP) ldA(0);
  setSC(0);
  pfS(1);

  // fully unrolled: ring indices compile-time, no scratch
  #pragma unroll
  for (int i = 0; i < NCH; ++i) {
    if (WSP && i + 1 < NCH) ldA(i + 1);        // coalesced 1-KB A loads
    if (i + 3 < NCH) pfB(i + 3);               // deep qw prefetch

    union { i32x4 i4; s16x8 s8; } u0, u1;
    u0.i4 = dq8(pB0[i & 3], s0, C0);
    u1.i4 = dq8(pB1[i & 3], s1, C1);

    #pragma unroll
    for (int r = 0; r < 4; ++r) {
      const s16x8 af = WSP ? pA[i & 1][r] : ldA_f32(i, r);
      acc[r * 2 + 0] = __builtin_amdgcn_mfma_f32_16x16x32_bf16(af, u0.s8, acc[r * 2 + 0], 0, 0, 0);
      acc[r * 2 + 1] = __builtin_amdgcn_mfma_f32_16x16x32_bf16(af, u1.s8, acc[r * 2 + 1], 0, 0, 0);
    }

    if ((i & 3) == 3) {
      const int g = i >> 2;
      if (g + 1 < NG) { setSC(g + 1); if (g + 2 < NG) pfS(g + 2); }
    }
  }

  // ---- epilogue: rows r*16 + quad*4 + j, cols ncol + t*16 ----
  if (WSP) {
    float* wsp = out + (size_t)ks * (MM * NN);
    #pragma unroll
    for (int r = 0; r < 4; ++r) {
      #pragma unroll
      for (int t = 0; t < 2; ++t) {
        const f32x4 a = acc[r * 2 + t];
        float* op = wsp + (size_t)(r * 16 + quad * 4) * NN + ncol + t * 16;
        op[0]      = a.x;
        op[NN]     = a.y;
        op[2 * NN] = a.z;
        op[3 * NN] = a.w;
      }
    }
  } else {
    #pragma unroll
    for (int r = 0; r < 4; ++r) {
      #pragma unroll
      for (int t = 0; t < 2; ++t) {
        const f32x4 a = acc[r * 2 + t];
        float* op = out + (size_t)(r * 16 + quad * 4) * NN + ncol + t * 16;
        atomicAdd(&op[0],      a.x);
        atomicAdd(&op[NN],     a.y);
        atomicAdd(&op[2 * NN], a.z);
        atomicAdd(&op[3 * NN], a.w);
      }
    }
  }
}

} // namespace

extern "C" void kernel_launch(void* const* d_in, const int* in_sizes, int n_in,
                              void* d_out, int out_size, void* d_ws, size_t ws_size,
                              hipStream_t stream) {
  const float* x      = (const float*)d_in[0];
  const int*   qw     = (const int*)d_in[1];
  const int*   qz     = (const int*)d_in[2];
  const float* scales = (const float*)d_in[3];
  const float* bias   = (const float*)d_in[4];
  float* out = (float*)d_out;

  if (ws_size >= WS_NEED) {
    float* ws = (float*)d_ws;
    unsigned short* xbt = (unsigned short*)((char*)d_ws + XBT_OFF);
    xcvt_kernel<<<(MM * KK / 8) / 256, 256, 0, stream>>>(x, xbt);
    gptq_gemm_kernel<true><<<NT * KSPLIT, 256, 0, stream>>>(x, qw, qz, scales, xbt, ws);
    reduce_kernel<<<(MM * NN) / 1024, 256, 0, stream>>>(ws, bias, out);
  } else {
    prep_kernel<<<(MM * NN) / 256, 256, 0, stream>>>(bias, out);
    gptq_gemm_kernel<false><<<NT * KSPLIT, 256, 0, stream>>>(x, qw, qz, scales, nullptr, out);
  }
}

// Round 7
// 99.907 us; speedup vs baseline: 1.6706x; 1.0259x over previous
//
#include <hip/hip_runtime.h>
#include <hip/hip_bf16.h>

namespace {

constexpr int MM = 64;
constexpr int KK = 4096;
constexpr int NN = 11008;
constexpr int NZROW = NN / 8;        // 1376
constexpr int BCOL = 128;            // cols per block = 4 waves x 32
constexpr int KSPLIT = 8;
constexpr int KSEG = KK / KSPLIT;    // 512
constexpr int BK = 32;               // k per chunk (one MFMA K)
constexpr int NCH = KSEG / BK;       // 16 chunks per kseg
constexpr int NG = KSEG / 128;       // 4 scale-groups per kseg
constexpr int NT = NN / BCOL;        // 86 col-tiles -> grid 688
constexpr size_t WS_NEED = (size_t)KSPLIT * MM * NN * 4;   // 22.5 MB partials

typedef float f32x4 __attribute__((ext_vector_type(4)));
typedef short s16x8 __attribute__((ext_vector_type(8)));
typedef int   i32x4 __attribute__((ext_vector_type(4)));

__device__ __forceinline__ int pack_bf16(float a, float b) {
  union { __hip_bfloat162 h; int i; } u;
  u.h.x = __float2bfloat16(a);
  u.h.y = __float2bfloat16(b);
  return u.i;
}

// fallback path only: out[m][n] = bias[n], atomics on top
__global__ __launch_bounds__(256) void prep_kernel(
    const float* __restrict__ bias, float* __restrict__ out)
{
  const int i = blockIdx.x * 256 + threadIdx.x;
  out[i] = bias[i % NN];
}

// ws path: out = bias + sum of KSPLIT partials
__global__ __launch_bounds__(256) void reduce_kernel(
    const float* __restrict__ ws, const float* __restrict__ bias,
    float* __restrict__ out)
{
  const int i4 = (blockIdx.x * 256 + threadIdx.x) * 4;
  f32x4 acc = *(const f32x4*)(bias + (i4 % NN));
  #pragma unroll
  for (int s = 0; s < KSPLIT; ++s)
    acc += *(const f32x4*)(ws + (size_t)s * (MM * NN) + i4);
  *(f32x4*)(out + i4) = acc;
}

// R12: A staged ONCE per block into 64 KB LDS as MFMA fragments, swizzled;
// one LDS-only barrier total; hot loop = 4 ds_read_b128 + register-direct
// B dequant + 16 MFMA per chunk. No xcvt kernel (2 dispatches total).
//
// LDS layout: fragment slot S = (ci*4 + r)*64 + lane', swizzled
// S' = S ^ ((S>>8)&7) (XOR hits only lane' bits 0-2). Analytically:
//  - hot-loop read (fixed ci,r): 64 lanes at 16B stride, perm by XOR const
//    -> canonical conflict-free b128 pattern;
//  - staging write (lane l covers k=l*8 of row m): bank-quad index
//    (m&7)^(l>>2 &7) -> 8 lanes per bank-quad, balanced, conflict-free.
// Staging global reads: lane reads 32 contiguous bytes, wave = 2 KB row.
// B path identical to R11 (one qweight dword = one MFMA B-fragment;
// exact 2^23 dequant, single rounding -> absmax 0.125 unchanged).
template<bool ATOMIC>
__global__ __launch_bounds__(256, 4) void gptq_gemm_kernel(
    const float* __restrict__ x, const int* __restrict__ qw,
    const int* __restrict__ qz, const float* __restrict__ scales,
    float* __restrict__ out)
{
  __shared__ int As[16384];   // 4096 fragment slots x 16 B = 64 KB

  const int tid  = threadIdx.x;
  const int wave = tid >> 6;
  const int lane = tid & 63;
  const int c    = lane & 15;
  const int quad = lane >> 4;

  const int ks     = blockIdx.x & 7;
  const int nt     = blockIdx.x >> 3;
  const int n0     = nt * BCOL;
  const int kbase0 = ks * KSEG;
  const int grp0   = kbase0 >> 7;          // scale-group base = ks*4

  const int ncol = n0 + wave * 32 + c;     // t=0 col; t=1 is ncol+16

  // B: qw row (kbase0/8 + quad), col ncol; chunk i advances 4 qw-rows
  const int* qwb = qw + ((size_t)(kbase0 >> 3) + quad) * NN + ncol;

  f32x4 acc[8];   // acc[r*2+t]
  #pragma unroll
  for (int t = 0; t < 8; ++t) acc[t] = {0.f, 0.f, 0.f, 0.f};

  int   pB0[4], pB1[4];  // qweight ring, depth-3 (cold HBM stream)
  float pS0[2], pS1[2];  // scales
  int   pZ0[2], pZ1[2];  // qzeros
  float s0, s1, C0, C1;  // current-group dequant constants

  auto pfB = [&](int i) {
    const int* qp = qwb + (size_t)i * 4 * NN;
    pB0[i & 3] = qp[0];
    pB1[i & 3] = qp[16];
  };
  auto pfS = [&](int g) {
    const int sl = g & 1;
    const float* sp = scales + (size_t)(grp0 + g) * NN + ncol;
    pS0[sl] = sp[0];
    pS1[sl] = sp[16];
    const int* zp = qz + (size_t)(grp0 + g) * NZROW + (ncol >> 3);
    pZ0[sl] = zp[0];
    pZ1[sl] = zp[2];   // (ncol+16)>>3 == (ncol>>3)+2
  };
  auto setSC = [&](int g) {
    const int sl = g & 1;
    const int sh = (ncol & 7) * 4;       // same nibble for ncol and ncol+16
    s0 = pS0[sl];
    s1 = pS1[sl];
    C0 = __int_as_float(0x4B000000 + ((pZ0[sl] >> sh) & 15) + 1);
    C1 = __int_as_float(0x4B000000 + ((pZ1[sl] >> sh) & 15) + 1);
  };
  auto dq8 = [&](int v, float s, float C) -> i32x4 {
    i32x4 p;
    p.x = pack_bf16(s * (__int_as_float(((v      ) & 15) | 0x4B000000) - C),
                    s * (__int_as_float(((v >>  4) & 15) | 0x4B000000) - C));
    p.y = pack_bf16(s * (__int_as_float(((v >>  8) & 15) | 0x4B000000) - C),
                    s * (__int_as_float(((v >> 12) & 15) | 0x4B000000) - C));
    p.z = pack_bf16(s * (__int_as_float(((v >> 16) & 15) | 0x4B000000) - C),
                    s * (__int_as_float(((v >> 20) & 15) | 0x4B000000) - C));
    p.w = pack_bf16(s * (__int_as_float(((v >> 24) & 15) | 0x4B000000) - C),
                    s * (__int_as_float(((v >> 28) & 15) | 0x4B000000) - C));
    return p;
  };

  // ---- prologue: get the qw/scale stream flying first ----
  pfS(0);
  pfB(0); pfB(1); pfB(2);
  pfS(1);

  // ---- stage A: wave stages rows m = wave*16 .. +15, full 512 k ----
  // lane l covers k = kbase0 + l*8 (+j): ci = l>>2, quad' = l&3.
  // Fragment G = ci*4 + (m>>4) = ci*4 + wave; lane' = (m&15) + (l&3)*16.
  // Swizzled int offset = G*256 + (l&3)*64 + ((m&15) ^ (ci&7))*4.
  {
    const int ciW = lane >> 2;
    const int cw  = ciW & 7;
    const int wconst = (ciW * 4 + wave) * 256 + (lane & 3) * 64;
    const float* xsb = x + (size_t)(wave * 16) * KK + kbase0 + lane * 8;
    #pragma unroll
    for (int rr = 0; rr < 16; ++rr) {
      const float* xp = xsb + (size_t)rr * KK;
      const f32x4 a0 = *(const f32x4*)xp;
      const f32x4 a1 = *(const f32x4*)(xp + 4);
      i32x4 pa;
      pa.x = pack_bf16(a0.x, a0.y);
      pa.y = pack_bf16(a0.z, a0.w);
      pa.z = pack_bf16(a1.x, a1.y);
      pa.w = pack_bf16(a1.z, a1.w);
      *(i32x4*)&As[wconst + ((rr ^ cw) << 2)] = pa;
    }
  }
  // LDS-only barrier: ds_writes drained, qw prefetch vmcnt stays in flight
  __asm__ volatile("s_waitcnt lgkmcnt(0)\n\ts_barrier" ::: "memory");
  setSC(0);

  // ---- main loop: zero barriers, zero global A ----
  #pragma unroll
  for (int i = 0; i < NCH; ++i) {
    if (i + 3 < NCH) pfB(i + 3);               // deep qw prefetch

    union { i32x4 i4; s16x8 s8; } u0, u1;
    u0.i4 = dq8(pB0[i & 3], s0, C0);
    u1.i4 = dq8(pB1[i & 3], s1, C1);

    // A fragments from LDS: base varies by lane^(i&7), (i,r) in imm offset
    const int rbase = (lane ^ (i & 7)) << 2;
    #pragma unroll
    for (int r = 0; r < 4; ++r) {
      const s16x8 af = *(const s16x8*)&As[rbase + (i * 4 + r) * 256];
      acc[r * 2 + 0] = __builtin_amdgcn_mfma_f32_16x16x32_bf16(af, u0.s8, acc[r * 2 + 0], 0, 0, 0);
      acc[r * 2 + 1] = __builtin_amdgcn_mfma_f32_16x16x32_bf16(af, u1.s8, acc[r * 2 + 1], 0, 0, 0);
    }

    if ((i & 3) == 3) {
      const int g = i >> 2;
      if (g + 1 < NG) { setSC(g + 1); if (g + 2 < NG) pfS(g + 2); }
    }
  }

  // ---- epilogue: rows r*16 + quad*4 + j, cols ncol + t*16 ----
  if (ATOMIC) {
    #pragma unroll
    for (int r = 0; r < 4; ++r) {
      #pragma unroll
      for (int t = 0; t < 2; ++t) {
        const f32x4 a = acc[r * 2 + t];
        float* op = out + (size_t)(r * 16 + quad * 4) * NN + ncol + t * 16;
        atomicAdd(&op[0],      a.x);
        atomicAdd(&op[NN],     a.y);
        atomicAdd(&op[2 * NN], a.z);
        atomicAdd(&op[3 * NN], a.w);
      }
    }
  } else {
    float* wsp = out + (size_t)ks * (MM * NN);
    #pragma unroll
    for (int r = 0; r < 4; ++r) {
      #pragma unroll
      for (int t = 0; t < 2; ++t) {
        const f32x4 a = acc[r * 2 + t];
        float* op = wsp + (size_t)(r * 16 + quad * 4) * NN + ncol + t * 16;
        op[0]      = a.x;
        op[NN]     = a.y;
        op[2 * NN] = a.z;
        op[3 * NN] = a.w;
      }
    }
  }
}

} // namespace

extern "C" void kernel_launch(void* const* d_in, const int* in_sizes, int n_in,
                              void* d_out, int out_size, void* d_ws, size_t ws_size,
                              hipStream_t stream) {
  const float* x      = (const float*)d_in[0];
  const int*   qw     = (const int*)d_in[1];
  const int*   qz     = (const int*)d_in[2];
  const float* scales = (const float*)d_in[3];
  const float* bias   = (const float*)d_in[4];
  float* out = (float*)d_out;

  if (ws_size >= WS_NEED) {
    float* ws = (float*)d_ws;
    gptq_gemm_kernel<false><<<NT * KSPLIT, 256, 0, stream>>>(x, qw, qz, scales, ws);
    reduce_kernel<<<(MM * NN) / 1024, 256, 0, stream>>>(ws, bias, out);
  } else {
    prep_kernel<<<(MM * NN) / 256, 256, 0, stream>>>(bias, out);
    gptq_gemm_kernel<true><<<NT * KSPLIT, 256, 0, stream>>>(x, qw, qz, scales, out);
  }
}